// Round 1
// baseline (142.469 us; speedup 1.0000x reference)
//
#include <hip/hip_runtime.h>

// h_t = (1 - f_t) * z_t + f_t * h_{t-1},  h_{-1} = 0, scanned along last axis S.
// Shapes: f, z, out all (B, H, S) = (32, 1024, 2048) fp32, contiguous in S.
// One block (256 threads) per row; 8 elements per thread; wave shfl scan +
// tiny LDS stitch across the 4 waves.

#define SEQ_LEN 2048
#define THREADS 256
#define PER_THREAD 8   // SEQ_LEN / THREADS

__global__ __launch_bounds__(THREADS) void fpool_scan_kernel(
    const float* __restrict__ f,
    const float* __restrict__ z,
    float* __restrict__ out)
{
    const long long row  = blockIdx.x;
    const long long base = row * (long long)SEQ_LEN;
    const int tid  = threadIdx.x;
    const int lane = tid & 63;
    const int wave = tid >> 6;

    // ---- load 8 contiguous elements as two float4 each for f and z ----
    const float4* f4 = reinterpret_cast<const float4*>(f + base);
    const float4* z4 = reinterpret_cast<const float4*>(z + base);
    float4 fa = f4[tid * 2 + 0];
    float4 fb = f4[tid * 2 + 1];
    float4 za = z4[tid * 2 + 0];
    float4 zb = z4[tid * 2 + 1];

    float av[PER_THREAD] = {fa.x, fa.y, fa.z, fa.w, fb.x, fb.y, fb.z, fb.w};
    float zv[PER_THREAD] = {za.x, za.y, za.z, za.w, zb.x, zb.y, zb.z, zb.w};

    // ---- local prefix transform within the 8-element chunk ----
    // T(h) = p*h + l ; element transform: h -> a*h + (1-a)*z
    float P[PER_THREAD], L[PER_THREAD];
    float p = 1.0f, l = 0.0f;
#pragma unroll
    for (int i = 0; i < PER_THREAD; ++i) {
        const float ai = av[i];
        const float bi = (1.0f - ai) * zv[i];
        l = fmaf(ai, l, bi);   // compose: apply element i after current prefix
        p = p * ai;
        P[i] = p;
        L[i] = l;
    }

    // ---- wave-level inclusive Hillis-Steele scan of chunk transforms ----
    // compose(earlier=(pp,pl), later=(cp,cl)) = (pp*cp, cp*pl + cl)
    float cp = p, cl = l;
#pragma unroll
    for (int d = 1; d < 64; d <<= 1) {
        float pp = __shfl_up(cp, d);
        float pl = __shfl_up(cl, d);
        if (lane >= d) {
            cl = fmaf(cp, pl, cl);
            cp = cp * pp;
        }
    }

    // ---- stitch waves via LDS (wave totals at lane 63) ----
    __shared__ float wp[THREADS / 64];
    __shared__ float wl[THREADS / 64];
    if (lane == 63) { wp[wave] = cp; wl[wave] = cl; }
    __syncthreads();

    // h entering this wave: apply previous waves' transforms to h = 0
    float h_wave = 0.0f;
#pragma unroll
    for (int w = 0; w < THREADS / 64; ++w) {
        if (w < wave) h_wave = fmaf(wp[w], h_wave, wl[w]);
    }

    // exclusive scan within wave: shift inclusive by one lane
    float ep = __shfl_up(cp, 1);
    float el = __shfl_up(cl, 1);
    if (lane == 0) { ep = 1.0f; el = 0.0f; }

    const float h_in = fmaf(ep, h_wave, el);  // h before this thread's chunk

    // ---- finalize and store ----
    float o[PER_THREAD];
#pragma unroll
    for (int i = 0; i < PER_THREAD; ++i) o[i] = fmaf(P[i], h_in, L[i]);

    float4* o4 = reinterpret_cast<float4*>(out + base);
    o4[tid * 2 + 0] = make_float4(o[0], o[1], o[2], o[3]);
    o4[tid * 2 + 1] = make_float4(o[4], o[5], o[6], o[7]);
}

extern "C" void kernel_launch(void* const* d_in, const int* in_sizes, int n_in,
                              void* d_out, int out_size, void* d_ws, size_t ws_size,
                              hipStream_t stream) {
    const float* f = reinterpret_cast<const float*>(d_in[0]);
    const float* z = reinterpret_cast<const float*>(d_in[1]);
    float* out = reinterpret_cast<float*>(d_out);

    const long long total = in_sizes[0];          // B*H*S
    const int rows = (int)(total / SEQ_LEN);      // B*H = 32768

    fpool_scan_kernel<<<rows, THREADS, 0, stream>>>(f, z, out);
}